// Round 5
// baseline (68.976 us; speedup 1.0000x reference)
//
#include <hip/hip_runtime.h>

// LinearQuant: out = clamp(floor(x*16 + 0.5), -128, 127) * 0.0625
// Elementwise, memory-bound. fp32 in -> fp32 out. N = 51,380,224 (÷4 clean).
//
// R4 post-mortem: sc0 sc1 (system-scope) stores bypass L2 while the
// harness's d_out memset leaves dirty zero lines in per-XCD L2 -> those
// lines evict OVER our HBM data. Unsafe without an L2 flush. Reverted.
//
// This is the R3 kernel (68.7 us, 95% of the 6.29 TB/s copy ceiling):
//  - unroll x4: 4 coalesced 16B loads in flight per thread per iteration
//  - __builtin_nontemporal_store (nt only, L2-coherent, correct)

typedef float f32x4 __attribute__((ext_vector_type(4)));

__device__ __forceinline__ float quant1(float x) {
    float r = floorf(fmaf(x, 16.0f, 0.5f));
    r = fminf(fmaxf(r, -128.0f), 127.0f);
    return r * 0.0625f;
}

__device__ __forceinline__ f32x4 quant4(f32x4 v) {
    f32x4 o;
    o.x = quant1(v.x);
    o.y = quant1(v.y);
    o.z = quant1(v.z);
    o.w = quant1(v.w);
    return o;
}

__global__ void __launch_bounds__(256) LinearQuant_kernel(
        const f32x4* __restrict__ in4, f32x4* __restrict__ out4, int n4) {
    const int T = gridDim.x * blockDim.x;
    int i = blockIdx.x * blockDim.x + threadIdx.x;

    // Main: 4 loads in flight before any store.
    for (; i + 3 * T < n4; i += 4 * T) {
        f32x4 v0 = in4[i];
        f32x4 v1 = in4[i + T];
        f32x4 v2 = in4[i + 2 * T];
        f32x4 v3 = in4[i + 3 * T];
        __builtin_nontemporal_store(quant4(v0), &out4[i]);
        __builtin_nontemporal_store(quant4(v1), &out4[i + T]);
        __builtin_nontemporal_store(quant4(v2), &out4[i + 2 * T]);
        __builtin_nontemporal_store(quant4(v3), &out4[i + 3 * T]);
    }
    // Remainder.
    for (; i < n4; i += T) {
        __builtin_nontemporal_store(quant4(in4[i]), &out4[i]);
    }
}

__global__ void __launch_bounds__(256) LinearQuant_tail(
        const float* __restrict__ in, float* __restrict__ out, int start, int n) {
    int i = start + blockIdx.x * blockDim.x + threadIdx.x;
    if (i < n) out[i] = quant1(in[i]);
}

extern "C" void kernel_launch(void* const* d_in, const int* in_sizes, int n_in,
                              void* d_out, int out_size, void* d_ws, size_t ws_size,
                              hipStream_t stream) {
    const float* x = (const float*)d_in[0];
    float* out = (float*)d_out;
    int n = in_sizes[0];
    int n4 = n / 4;

    int blocks = (n4 + 255) / 256;
    if (blocks > 2048) blocks = 2048;
    if (blocks < 1) blocks = 1;
    LinearQuant_kernel<<<blocks, 256, 0, stream>>>(
        (const f32x4*)x, (f32x4*)out, n4);

    int tail_start = n4 * 4;
    int tail = n - tail_start;
    if (tail > 0) {
        LinearQuant_tail<<<1, 256, 0, stream>>>(x, out, tail_start, n);
    }
}